// Round 4
// baseline (728.312 us; speedup 1.0000x reference)
//
#include <hip/hip_runtime.h>
#include <hip/hip_bf16.h>
#include <math.h>

#define B_    2048
#define IND   20000
#define ENCN  512
#define BOTN  128
#define DECN  512
#define KP1   20480   // IND padded to 64*320
#define NP    20224   // IND padded to 79*256
#define SPLITK 16
#define KSTEP1 20     // 16*20*64 = 20480
#define SPLITK2 4
#define BNEPS 1e-5f

typedef __hip_bfloat16 bf16;
typedef __bf16 bf16x8 __attribute__((ext_vector_type(8)));
typedef float f32x4 __attribute__((ext_vector_type(4)));
typedef unsigned short u16;

__device__ __forceinline__ u16 f2bfu(float f) {
  __hip_bfloat16 h = __float2bfloat16(f);
  return *reinterpret_cast<u16*>(&h);
}

__device__ __forceinline__ void st_b64_bf16(void* p, f32x4 v) {
  union { u16 u[4]; uint2 d; } o;
  o.u[0] = f2bfu(v[0]); o.u[1] = f2bfu(v[1]);
  o.u[2] = f2bfu(v[2]); o.u[3] = f2bfu(v[3]);
  *(uint2*)p = o.d;
}

__device__ __forceinline__ void gload_lds16(const bf16* g, bf16* l) {
  __builtin_amdgcn_global_load_lds(
      (const __attribute__((address_space(1))) void*)g,
      (__attribute__((address_space(3))) void*)l, 16, 0, 0);
}

// ---------------- row sums ----------------
__global__ void rowsum_k(const float* __restrict__ x, float* __restrict__ row_sum) {
  const int row = blockIdx.x;
  const f32x4* xr = (const f32x4*)(x + (size_t)row * IND);
  float s = 0.f;
  for (int i = threadIdx.x; i < IND / 4; i += 256) {
    f32x4 v = xr[i];
    s += (v[0] + v[1]) + (v[2] + v[3]);
  }
#pragma unroll
  for (int o = 32; o > 0; o >>= 1) s += __shfl_down(s, o, 64);
  __shared__ float ws4[4];
  if ((threadIdx.x & 63) == 0) ws4[threadIdx.x >> 6] = s;
  __syncthreads();
  if (threadIdx.x == 0) row_sum[row] = (ws4[0] + ws4[1]) + (ws4[2] + ws4[3]);
}

// ---------------- median + per-row scale ----------------
__global__ void median_scale_k(const float* __restrict__ row_sum,
                               float* __restrict__ sArr, float* __restrict__ invs) {
  __shared__ float v[B_];
  const int tid = threadIdx.x;  // 1024 threads
  v[tid] = row_sum[tid];
  v[tid + 1024] = row_sum[tid + 1024];
  __syncthreads();
  for (int k = 2; k <= B_; k <<= 1) {
    for (int j = k >> 1; j > 0; j >>= 1) {
      for (int i = tid; i < B_; i += 1024) {
        int ixj = i ^ j;
        if (ixj > i) {
          bool up = ((i & k) == 0);
          float a = v[i], b = v[ixj];
          if ((a > b) == up) { v[i] = b; v[ixj] = a; }
        }
      }
      __syncthreads();
    }
  }
  float med = 0.5f * (v[B_ / 2 - 1] + v[B_ / 2]);
  for (int i = tid; i < B_; i += 1024) {
    float rs = row_sum[i];
    sArr[i] = rs / med;
    invs[i] = med / rs;
  }
}

// ---------------- pass2: L = bf16(log1p(x*invs)), partial col sums/sumsq ----------------
__global__ void pass2_k(const float* __restrict__ x, const float* __restrict__ invs,
                        bf16* __restrict__ L, float* __restrict__ part_s,
                        float* __restrict__ part_q) {
  const int c0 = (blockIdx.x * 256 + threadIdx.x) * 4;   // 0..20476
  const int rblk = blockIdx.y;
  const int r0 = rblk * 32;
  const bool valid = (c0 < IND);
  f32x4 sum = {0.f, 0.f, 0.f, 0.f}, sq = {0.f, 0.f, 0.f, 0.f};
  for (int r = r0; r < r0 + 32; ++r) {
    f32x4 lv = {0.f, 0.f, 0.f, 0.f};
    if (valid) {
      f32x4 v = *(const f32x4*)(x + (size_t)r * IND + c0);
      float iv = invs[r];
      lv[0] = log1pf(v[0] * iv); lv[1] = log1pf(v[1] * iv);
      lv[2] = log1pf(v[2] * iv); lv[3] = log1pf(v[3] * iv);
      sum += lv; sq += lv * lv;
    }
    ushort4 o;
    o.x = f2bfu(lv[0]); o.y = f2bfu(lv[1]); o.z = f2bfu(lv[2]); o.w = f2bfu(lv[3]);
    *(ushort4*)((u16*)L + (size_t)r * KP1 + c0) = o;
  }
  if (valid) {
    *(f32x4*)(part_s + (size_t)rblk * KP1 + c0) = sum;
    *(f32x4*)(part_q + (size_t)rblk * KP1 + c0) = sq;
  }
}

// ---------------- finalize BN0 from 64 partials ----------------
__global__ void finalize_bn_k(const float* __restrict__ part_s, const float* __restrict__ part_q,
                              const float* __restrict__ g, const float* __restrict__ b,
                              float* __restrict__ scale, float* __restrict__ shift) {
  int c = blockIdx.x * 256 + threadIdx.x;
  if (c >= IND) return;
  float s = 0.f, q = 0.f;
  for (int z = 0; z < 64; ++z) {
    s += part_s[(size_t)z * KP1 + c];
    q += part_q[(size_t)z * KP1 + c];
  }
  const float invN = 1.f / (float)B_;
  float mean = s * invN;
  float var = q * invN - mean * mean;
  float sc = g[c] * rsqrtf(var + BNEPS);
  scale[c] = sc;
  shift[c] = b[c] - mean * sc;
}

// ---------------- W' = bf16(enc_W * scale0), bias1 = enc_b + shift0 . enc_W^T ----------------
__global__ void prepw_k(const float* __restrict__ encW, const float* __restrict__ enc_b,
                        const float* __restrict__ scale0, const float* __restrict__ shift0,
                        bf16* __restrict__ Wp, float* __restrict__ bias1) {
  const int e = blockIdx.x;  // 512
  float local = 0.f;
  for (int j0 = threadIdx.x * 4; j0 < KP1; j0 += 1024) {
    ushort4 o;
    if (j0 < IND) {
      f32x4 w = *(const f32x4*)(encW + (size_t)e * IND + j0);
      f32x4 sc = *(const f32x4*)(scale0 + j0);
      f32x4 sh = *(const f32x4*)(shift0 + j0);
      local += sh[0] * w[0] + sh[1] * w[1] + sh[2] * w[2] + sh[3] * w[3];
      o.x = f2bfu(w[0] * sc[0]); o.y = f2bfu(w[1] * sc[1]);
      o.z = f2bfu(w[2] * sc[2]); o.w = f2bfu(w[3] * sc[3]);
    } else {
      o.x = 0; o.y = 0; o.z = 0; o.w = 0;
    }
    *(ushort4*)((u16*)Wp + (size_t)e * KP1 + j0) = o;
  }
#pragma unroll
  for (int o = 32; o > 0; o >>= 1) local += __shfl_down(local, o, 64);
  __shared__ float red[4];
  if ((threadIdx.x & 63) == 0) red[threadIdx.x >> 6] = local;
  __syncthreads();
  if (threadIdx.x == 0) bias1[e] = enc_b[e] + ((red[0] + red[1]) + (red[2] + red[3]));
}

// ---------------- GEMM1: 256x256 8-wave 2-phase dbuf, split-K=16 ----------------
__global__ __launch_bounds__(512, 2)
void gemm1_k(const bf16* __restrict__ A, const bf16* __restrict__ Bm,
             float* __restrict__ Cp) {
  extern __shared__ __align__(16) bf16 smem[];  // 128 KiB
  bf16* AsB = smem;           // [2][16384]
  bf16* BsB = smem + 32768;   // [2][16384]
  const int tid = threadIdx.x;
  const int lane = tid & 63;
  const int wave = tid >> 6;
  const int wr = wave >> 2;
  const int wc = wave & 3;

  // chunked XCD swizzle, nwg = 256
  const int bid = blockIdx.x;
  const int swz = (bid & 7) * 32 + (bid >> 3);
  const int xm = swz & 7;
  const int rest = swz >> 3;
  const int yn = rest & 1;
  const int z = rest >> 1;
  const int m0 = xm * 256;
  const int n0 = yn * 256;
  const int kbeg = z * KSTEP1 * 64;

  const int srow = tid >> 3;
  const int schunk = (tid & 7) ^ (srow & 7);
  const bf16* gA = A + (size_t)(m0 + srow) * KP1 + kbeg + schunk * 8;
  const bf16* gB = Bm + (size_t)(n0 + srow) * KP1 + kbeg + schunk * 8;
  const int ldst = tid * 8;

  f32x4 acc[8][4] = {};
  const int lrow = lane & 15;
  const int kq = lane >> 4;

  auto STAGE = [&](int ks, int buf) {
    const bf16* ga = gA + (size_t)ks * 64;
    const bf16* gb = gB + (size_t)ks * 64;
    bf16* la = AsB + buf * 16384 + ldst;
    bf16* lb = BsB + buf * 16384 + ldst;
#pragma unroll
    for (int i = 0; i < 4; ++i) {
      gload_lds16(ga + (size_t)(i * 64) * KP1, la + i * 4096);
      gload_lds16(gb + (size_t)(i * 64) * KP1, lb + i * 4096);
    }
  };

  STAGE(0, 0);
  asm volatile("s_waitcnt vmcnt(0)" ::: "memory");
  __builtin_amdgcn_s_barrier();

  int cur = 0;
  for (int ks = 0; ks < KSTEP1; ++ks) {
    if (ks + 1 < KSTEP1) STAGE(ks + 1, cur ^ 1);
    const bf16* As = AsB + cur * 16384;
    const bf16* Bs = BsB + cur * 16384;
#pragma unroll
    for (int kk = 0; kk < 2; ++kk) {
      const int kc = kk * 4 + kq;
      bf16x8 af[8], bfv[4];
#pragma unroll
      for (int m = 0; m < 8; ++m) {
        const int row = wr * 128 + m * 16 + lrow;
        af[m] = *(const bf16x8*)(&As[row * 64 + ((kc ^ (row & 7)) << 3)]);
      }
#pragma unroll
      for (int n = 0; n < 4; ++n) {
        const int row = wc * 64 + n * 16 + lrow;
        bfv[n] = *(const bf16x8*)(&Bs[row * 64 + ((kc ^ (row & 7)) << 3)]);
      }
#pragma unroll
      for (int m = 0; m < 8; ++m)
#pragma unroll
        for (int n = 0; n < 4; ++n)
          acc[m][n] = __builtin_amdgcn_mfma_f32_16x16x32_bf16(bfv[n], af[m], acc[m][n], 0, 0, 0);
    }
    if (ks + 1 < KSTEP1) {
      asm volatile("s_waitcnt vmcnt(0)" ::: "memory");
      __builtin_amdgcn_s_barrier();
      cur ^= 1;
    }
  }

  float* o0 = Cp + (size_t)z * ((size_t)B_ * ENCN);
  const int growb = m0 + wr * 128 + lrow;
  const int gcolb = n0 + wc * 64 + kq * 4;
#pragma unroll
  for (int m = 0; m < 8; ++m) {
    const int grow = growb + m * 16;
#pragma unroll
    for (int n = 0; n < 4; ++n) {
      const int gcol = gcolb + n * 16;
      *(f32x4*)(&o0[(size_t)grow * ENCN + gcol]) = acc[m][n];
    }
  }
}

// ---------------- combined output GEMMs: g in {0:pai,1:M+M_loss,2:theta} ----------------
__global__ __launch_bounds__(512, 2)
void gemm_out_k(const bf16* __restrict__ h3,
                const float* __restrict__ W0, const float* __restrict__ W1,
                const float* __restrict__ W2,
                const float* __restrict__ b0, const float* __restrict__ b1,
                const float* __restrict__ b2,
                const float* __restrict__ sArr, float* __restrict__ out) {
  extern __shared__ __align__(16) bf16 smem[];  // 128 KiB
  bf16* AsB = smem;           // [2][16384]
  bf16* BsB = smem + 32768;   // [2][16384]
  const int tid = threadIdx.x;
  const int lane = tid & 63;
  const int wave = tid >> 6;
  const int wr = wave >> 2;
  const int wc = wave & 3;

  // chunked XCD swizzle, nwg = 1896 (= 8 * 237)
  const int bid = blockIdx.x;
  const int swz = (bid & 7) * 237 + (bid >> 3);
  const int g = swz / 632;            // which GEMM
  const int r2 = swz - g * 632;
  const int xm = r2 & 7;
  const int yn = r2 >> 3;             // 0..78
  const int m0 = xm * 256;
  const int n0 = yn * 256;

  const float* Wg = (g == 0) ? W0 : (g == 1) ? W1 : W2;
  const float* bg = (g == 0) ? b0 : (g == 1) ? b1 : b2;
  const size_t OFF = (size_t)B_ * IND;
  float* o0 = out + (size_t)g * OFF;
  float* o1 = out + 3 * OFF;

  // A staging (global_load_lds, pre-swizzled source)
  const int srow = tid >> 3;
  const int schunk = (tid & 7) ^ (srow & 7);
  const bf16* gA = h3 + (size_t)(m0 + srow) * ENCN + schunk * 8;
  const int ldstA = tid * 8;

  // B staging (reg-staged f32 -> bf16, swizzled ds_write): 8 rows/thread
  const int lrow = lane & 15;
  const int kq = lane >> 4;
  const int bcol = lrow * 4;                // f32 col within 64-col step
  const int brow0 = wave * 32 + kq;         // + i*4

  f32x4 acc[8][4] = {};
  f32x4 bv[8];

  auto LOADA = [&](int ks, int buf) {
    const bf16* ga = gA + ks * 64;
    bf16* la = AsB + buf * 16384 + ldstA;
#pragma unroll
    for (int i = 0; i < 4; ++i)
      gload_lds16(ga + (size_t)(i * 64) * ENCN, la + i * 4096);
  };
  auto LOADB = [&](int ks) {
#pragma unroll
    for (int i = 0; i < 8; ++i) {
      const int gr = n0 + brow0 + i * 4;
      if (gr < IND) bv[i] = *(const f32x4*)(Wg + (size_t)gr * ENCN + ks * 64 + bcol);
      else bv[i] = f32x4{0.f, 0.f, 0.f, 0.f};
    }
  };
  auto WRITEB = [&](int buf) {
    char* lb = (char*)(BsB + buf * 16384);
#pragma unroll
    for (int i = 0; i < 8; ++i) {
      const int r = brow0 + i * 4;
      const int byte = r * 128 + (((lrow >> 1) ^ (r & 7)) << 4) + ((lrow & 1) << 3);
      st_b64_bf16(lb + byte, bv[i]);
    }
  };

  LOADB(0);
  LOADA(0, 0);
  WRITEB(0);
  __syncthreads();

  int cur = 0;
  for (int ks = 0; ks < 8; ++ks) {
    if (ks < 7) { LOADA(ks + 1, cur ^ 1); LOADB(ks + 1); }
    const bf16* As = AsB + cur * 16384;
    const bf16* Bs = BsB + cur * 16384;
#pragma unroll
    for (int kk = 0; kk < 2; ++kk) {
      const int kc = kk * 4 + kq;
      bf16x8 af[8], bfv[4];
#pragma unroll
      for (int m = 0; m < 8; ++m) {
        const int row = wr * 128 + m * 16 + lrow;
        af[m] = *(const bf16x8*)(&As[row * 64 + ((kc ^ (row & 7)) << 3)]);
      }
#pragma unroll
      for (int n = 0; n < 4; ++n) {
        const int row = wc * 64 + n * 16 + lrow;
        bfv[n] = *(const bf16x8*)(&Bs[row * 64 + ((kc ^ (row & 7)) << 3)]);
      }
#pragma unroll
      for (int m = 0; m < 8; ++m)
#pragma unroll
        for (int n = 0; n < 4; ++n)
          acc[m][n] = __builtin_amdgcn_mfma_f32_16x16x32_bf16(bfv[n], af[m], acc[m][n], 0, 0, 0);
    }
    if (ks < 7) {
      WRITEB(cur ^ 1);
      __syncthreads();
      cur ^= 1;
    }
  }

  const int growb = m0 + wr * 128 + lrow;
  const int gcolb = n0 + wc * 64 + kq * 4;
#pragma unroll
  for (int m = 0; m < 8; ++m) {
    const int grow = growb + m * 16;
    float ss = (g == 1) ? sArr[grow] : 0.f;
#pragma unroll
    for (int n = 0; n < 4; ++n) {
      const int gcol = gcolb + n * 16;
      if (gcol < IND) {
        f32x4 t = acc[m][n] + *(const f32x4*)(&bg[gcol]);
        f32x4 r;
        if (g == 0) {
#pragma unroll
          for (int j = 0; j < 4; ++j) r[j] = 1.f / (1.f + __expf(-t[j]));
          *(f32x4*)(&o0[(size_t)grow * IND + gcol]) = r;
        } else {
#pragma unroll
          for (int j = 0; j < 4; ++j) r[j] = __expf(t[j]);
          *(f32x4*)(&o0[(size_t)grow * IND + gcol]) = r;
          if (g == 1) {
            f32x4 rl;
#pragma unroll
            for (int j = 0; j < 4; ++j) rl[j] = ss * r[j];
            *(f32x4*)(&o1[(size_t)grow * IND + gcol]) = rl;
          }
        }
      }
    }
  }
}

// ---------------- mid GEMMs (128x128, 4-wave, f32 inputs staged w/ affine) ----------------
// EPI 0: raw f32x4 partial store to outP + z*B_*ldo (GEMM2 split-K)
// EPI 1: bias + relu -> bf16 outB (GEMM3 -> h3)
template <int EPI>
__global__ __launch_bounds__(256, 2)
void gemm_mid_k(const float* __restrict__ A, int lda,
                const float* __restrict__ scl, const float* __restrict__ sft,
                const float* __restrict__ W, int ldb,
                const float* __restrict__ bias,
                float* __restrict__ outP, bf16* __restrict__ outB, int ldo) {
  __shared__ __align__(16) bf16 As[128 * 64];
  __shared__ __align__(16) bf16 Bs[128 * 64];
  const int tid = threadIdx.x;
  const int lane = tid & 63;
  const int wave = tid >> 6;
  const int wr = wave >> 1, wc = wave & 1;
  const int m0 = blockIdx.x * 128;
  const int n0 = blockIdx.y * 128;
  const int z = blockIdx.z;
  const int kbeg = z * 128;
  const int lrow = lane & 15;
  const int kq = lane >> 4;
  const int scol = lrow * 4;
  const int srow0 = wave * 32 + kq;

  f32x4 acc[4][4] = {};
  for (int ks = 0; ks < 2; ++ks) {
    const int kb = kbeg + ks * 64;
    f32x4 sc4 = *(const f32x4*)(scl + kb + scol);
    f32x4 sf4 = *(const f32x4*)(sft + kb + scol);
#pragma unroll
    for (int i = 0; i < 8; ++i) {
      const int r = srow0 + i * 4;
      const int byte = r * 128 + (((lrow >> 1) ^ (r & 7)) << 4) + ((lrow & 1) << 3);
      f32x4 a = *(const f32x4*)(A + (size_t)(m0 + r) * lda + kb + scol);
      a = a * sc4 + sf4;
      st_b64_bf16((char*)As + byte, a);
      f32x4 b = *(const f32x4*)(W + (size_t)(n0 + r) * ldb + kb + scol);
      st_b64_bf16((char*)Bs + byte, b);
    }
    __syncthreads();
#pragma unroll
    for (int kk = 0; kk < 2; ++kk) {
      const int kc = kk * 4 + kq;
      bf16x8 af[4], bfv[4];
#pragma unroll
      for (int m = 0; m < 4; ++m) {
        const int row = wr * 64 + m * 16 + lrow;
        af[m] = *(const bf16x8*)(&As[row * 64 + ((kc ^ (row & 7)) << 3)]);
      }
#pragma unroll
      for (int n = 0; n < 4; ++n) {
        const int row = wc * 64 + n * 16 + lrow;
        bfv[n] = *(const bf16x8*)(&Bs[row * 64 + ((kc ^ (row & 7)) << 3)]);
      }
#pragma unroll
      for (int m = 0; m < 4; ++m)
#pragma unroll
        for (int n = 0; n < 4; ++n)
          acc[m][n] = __builtin_amdgcn_mfma_f32_16x16x32_bf16(bfv[n], af[m], acc[m][n], 0, 0, 0);
    }
    __syncthreads();
  }

  const int growb = m0 + wr * 64 + lrow;
  const int gcolb = n0 + wc * 64 + kq * 4;
#pragma unroll
  for (int m = 0; m < 4; ++m) {
    const int grow = growb + m * 16;
#pragma unroll
    for (int n = 0; n < 4; ++n) {
      const int gcol = gcolb + n * 16;
      if (EPI == 0) {
        float* op = outP + (size_t)z * ((size_t)B_ * ldo);
        *(f32x4*)(&op[(size_t)grow * ldo + gcol]) = acc[m][n];
      } else {
        f32x4 t = acc[m][n] + *(const f32x4*)(&bias[gcol]);
        f32x4 r;
#pragma unroll
        for (int j = 0; j < 4; ++j) r[j] = fmaxf(t[j], 0.f);
        st_b64_bf16((u16*)outB + (size_t)grow * ldo + gcol, r);
      }
    }
  }
}

// ---------------- split-K reduce + bias + relu + BN1 col-partials ----------------
__global__ void reduce1c_k(const float* __restrict__ Cp, const float* __restrict__ bias1,
                           float* __restrict__ C1, float* __restrict__ ps,
                           float* __restrict__ pq) {
  const int b = blockIdx.x;          // 256 blocks, 8 rows each
  const int t = threadIdx.x;         // 256
  const int c4 = (t & 127) * 4;
  const int rs = t >> 7;
  f32x4 bb = *(const f32x4*)(bias1 + c4);
  f32x4 sum = {0.f, 0.f, 0.f, 0.f}, sq = {0.f, 0.f, 0.f, 0.f};
#pragma unroll
  for (int rr = 0; rr < 4; ++rr) {
    const int row = b * 8 + rs + rr * 2;
    f32x4 v = {0.f, 0.f, 0.f, 0.f};
#pragma unroll
    for (int z = 0; z < SPLITK; ++z)
      v += *(const f32x4*)(Cp + (size_t)z * (B_ * ENCN) + (size_t)row * ENCN + c4);
    v += bb;
    f32x4 r;
#pragma unroll
    for (int j = 0; j < 4; ++j) r[j] = fmaxf(v[j], 0.f);
    *(f32x4*)(C1 + (size_t)row * ENCN + c4) = r;
    sum += r; sq += r * r;
  }
  __shared__ f32x4 ls[2][128], lq[2][128];
  ls[rs][t & 127] = sum; lq[rs][t & 127] = sq;
  __syncthreads();
  if (t < 128) {
    f32x4 s = ls[0][t] + ls[1][t];
    f32x4 q = lq[0][t] + lq[1][t];
    *(f32x4*)(ps + (size_t)b * ENCN + t * 4) = s;
    *(f32x4*)(pq + (size_t)b * ENCN + t * 4) = q;
  }
}

// ---------------- split-K reduce + bias + relu + BN2 col-partials (GEMM2) ----------------
__global__ void reduce2c_k(const float* __restrict__ Cp2, const float* __restrict__ bias,
                           float* __restrict__ C2, float* __restrict__ ps,
                           float* __restrict__ pq) {
  const int b = blockIdx.x;      // 128 blocks, 16 rows each
  const int t = threadIdx.x;     // 256
  const int c4 = (t & 31) * 4;
  const int rs = t >> 5;         // 0..7
  f32x4 bb = *(const f32x4*)(bias + c4);
  f32x4 sum = {0.f, 0.f, 0.f, 0.f}, sq = {0.f, 0.f, 0.f, 0.f};
#pragma unroll
  for (int rr = 0; rr < 2; ++rr) {
    const int row = b * 16 + rs + rr * 8;
    f32x4 v = {0.f, 0.f, 0.f, 0.f};
#pragma unroll
    for (int z = 0; z < SPLITK2; ++z)
      v += *(const f32x4*)(Cp2 + (size_t)z * (B_ * BOTN) + (size_t)row * BOTN + c4);
    v += bb;
    f32x4 r;
#pragma unroll
    for (int j = 0; j < 4; ++j) r[j] = fmaxf(v[j], 0.f);
    *(f32x4*)(C2 + (size_t)row * BOTN + c4) = r;
    sum += r; sq += r * r;
  }
  __shared__ f32x4 ls[8][32], lq[8][32];
  ls[rs][t & 31] = sum; lq[rs][t & 31] = sq;
  __syncthreads();
  if (t < 32) {
    f32x4 s = {0.f, 0.f, 0.f, 0.f}, q = {0.f, 0.f, 0.f, 0.f};
#pragma unroll
    for (int k = 0; k < 8; ++k) { s += ls[k][t]; q += lq[k][t]; }
    *(f32x4*)(ps + (size_t)b * BOTN + t * 4) = s;
    *(f32x4*)(pq + (size_t)b * BOTN + t * 4) = q;
  }
}

// ---------------- finalize BN1/BN2 scale+shift from partials ----------------
__global__ void colfin_k(const float* __restrict__ ps, const float* __restrict__ pq,
                         const float* __restrict__ g, const float* __restrict__ b,
                         float* __restrict__ scale, float* __restrict__ shift,
                         int C, int nPart) {
  const int cl = threadIdx.x & 63;
  const int pg = threadIdx.x >> 6;   // 0..3
  const int c = blockIdx.x * 64 + cl;
  float s = 0.f, q = 0.f;
  for (int p = pg; p < nPart; p += 4) {
    s += ps[(size_t)p * C + c];
    q += pq[(size_t)p * C + c];
  }
  __shared__ float ls[4][64], lq[4][64];
  ls[pg][cl] = s; lq[pg][cl] = q;
  __syncthreads();
  if (pg == 0) {
    s = (ls[0][cl] + ls[1][cl]) + (ls[2][cl] + ls[3][cl]);
    q = (lq[0][cl] + lq[1][cl]) + (lq[2][cl] + lq[3][cl]);
    const float invN = 1.f / (float)B_;
    float mean = s * invN;
    float var = q * invN - mean * mean;
    float sc = g[c] * rsqrtf(var + BNEPS);
    scale[c] = sc;
    shift[c] = b[c] - mean * sc;
  }
}

extern "C" void kernel_launch(void* const* d_in, const int* in_sizes, int n_in,
                              void* d_out, int out_size, void* d_ws, size_t ws_size,
                              hipStream_t stream) {
  const float* x     = (const float*)d_in[0];
  const float* bn0_g = (const float*)d_in[1];
  const float* bn0_b = (const float*)d_in[2];
  const float* enc_W = (const float*)d_in[3];
  const float* enc_b = (const float*)d_in[4];
  const float* bn1_g = (const float*)d_in[5];
  const float* bn1_b = (const float*)d_in[6];
  const float* bot_W = (const float*)d_in[7];
  const float* bot_b = (const float*)d_in[8];
  const float* bn2_g = (const float*)d_in[9];
  const float* bn2_b = (const float*)d_in[10];
  const float* dec_W = (const float*)d_in[11];
  const float* dec_b = (const float*)d_in[12];
  const float* o1_W  = (const float*)d_in[13];
  const float* o1_b  = (const float*)d_in[14];
  const float* o2_W  = (const float*)d_in[15];
  const float* o2_b  = (const float*)d_in[16];
  const float* o3_W  = (const float*)d_in[17];
  const float* o3_b  = (const float*)d_in[18];

  char* wsb = (char*)d_ws;
  size_t off = 0;
  auto alloc = [&](size_t bytes) -> void* {
    void* p = wsb + off;
    off = (off + bytes + 255) & ~(size_t)255;
    return p;
  };
  float* row_sum = (float*)alloc(B_ * 4);
  float* sArr    = (float*)alloc(B_ * 4);
  float* invs    = (float*)alloc(B_ * 4);
  float* scale0  = (float*)alloc(IND * 4);
  float* shift0  = (float*)alloc(IND * 4);
  float* bias1   = (float*)alloc(ENCN * 4);
  float* scale1  = (float*)alloc(ENCN * 4);
  float* shift1  = (float*)alloc(ENCN * 4);
  float* scale2  = (float*)alloc(BOTN * 4);
  float* shift2  = (float*)alloc(BOTN * 4);
  float* ps1     = (float*)alloc(256 * ENCN * 4);
  float* pq1     = (float*)alloc(256 * ENCN * 4);
  float* ps2     = (float*)alloc(128 * BOTN * 4);
  float* pq2     = (float*)alloc(128 * BOTN * 4);
  float* C1      = (float*)alloc((size_t)B_ * ENCN * 4);
  float* C2f     = (float*)alloc((size_t)B_ * BOTN * 4);
  float* Cp2     = (float*)alloc((size_t)SPLITK2 * B_ * BOTN * 4);
  float* Cp      = (float*)alloc((size_t)SPLITK * B_ * ENCN * 4);
  bf16*  L       = (bf16*)alloc((size_t)B_ * KP1 * 2);
  bf16*  Wp      = (bf16*)alloc((size_t)ENCN * KP1 * 2);
  bf16*  h3      = (bf16*)alloc((size_t)B_ * DECN * 2);
  // BN0 partials alias Cp (dead before GEMM1 writes Cp)
  float* part_s  = Cp;
  float* part_q  = Cp + (size_t)64 * KP1;

  hipFuncSetAttribute(reinterpret_cast<const void*>(gemm1_k),
                      hipFuncAttributeMaxDynamicSharedMemorySize, 131072);
  hipFuncSetAttribute(reinterpret_cast<const void*>(gemm_out_k),
                      hipFuncAttributeMaxDynamicSharedMemorySize, 131072);

  // 1. row sums + median scales
  rowsum_k<<<B_, 256, 0, stream>>>(x, row_sum);
  median_scale_k<<<1, 1024, 0, stream>>>(row_sum, sArr, invs);

  // 2. L = bf16(log1p(x/s)), BN0 stats
  pass2_k<<<dim3(KP1 / 1024, 64), 256, 0, stream>>>(x, invs, L, part_s, part_q);
  finalize_bn_k<<<(IND + 255) / 256, 256, 0, stream>>>(part_s, part_q, bn0_g, bn0_b,
                                                       scale0, shift0);

  // 3. fold BN0 into encoder weights
  prepw_k<<<ENCN, 256, 0, stream>>>(enc_W, enc_b, scale0, shift0, Wp, bias1);

  // 4. GEMM1 (256^2, split-K=16) + fused reduce(+bias+relu+BN1 partials)
  gemm1_k<<<256, 512, 131072, stream>>>(L, Wp, Cp);
  reduce1c_k<<<256, 256, 0, stream>>>(Cp, bias1, C1, ps1, pq1);
  colfin_k<<<ENCN / 64, 256, 0, stream>>>(ps1, pq1, bn1_g, bn1_b, scale1, shift1,
                                          ENCN, 256);

  // 5. GEMM2 (affine-fused staging, split-K=4) -> reduce -> BN2 -> GEMM3 -> h3
  gemm_mid_k<0><<<dim3(16, 1, SPLITK2), 256, 0, stream>>>(
      C1, ENCN, scale1, shift1, bot_W, ENCN, nullptr, Cp2, nullptr, BOTN);
  reduce2c_k<<<128, 256, 0, stream>>>(Cp2, bot_b, C2f, ps2, pq2);
  colfin_k<<<BOTN / 64, 256, 0, stream>>>(ps2, pq2, bn2_g, bn2_b, scale2, shift2,
                                          BOTN, 128);
  gemm_mid_k<1><<<dim3(16, 4, 1), 256, 0, stream>>>(
      C2f, BOTN, scale2, shift2, dec_W, BOTN, dec_b, nullptr, h3, DECN);

  // 6. combined output GEMMs (f32 weights staged directly, no cvt pass)
  float* out = (float*)d_out;
  gemm_out_k<<<1896, 512, 131072, stream>>>(h3, o2_W, o1_W, o3_W,
                                            o2_b, o1_b, o3_b, sArr, out);
}

// Round 5
// 670.471 us; speedup vs baseline: 1.0863x; 1.0863x over previous
//
#include <hip/hip_runtime.h>
#include <hip/hip_bf16.h>
#include <math.h>

#define B_    2048
#define IND   20000
#define ENCN  512
#define BOTN  128
#define DECN  512
#define KP1   20480   // IND padded to 64*320
#define NP    20224   // IND padded to 79*256
#define SPLITK 16
#define KSTEP1 20     // 16*20*64 = 20480
#define BNEPS 1e-5f

typedef __hip_bfloat16 bf16;
typedef __bf16 bf16x8 __attribute__((ext_vector_type(8)));
typedef float f32x4 __attribute__((ext_vector_type(4)));
typedef unsigned short u16;

__device__ __forceinline__ u16 f2bfu(float f) {
  __hip_bfloat16 h = __float2bfloat16(f);
  return *reinterpret_cast<u16*>(&h);
}

__device__ __forceinline__ void gload_lds16(const bf16* g, bf16* l) {
  __builtin_amdgcn_global_load_lds(
      (const __attribute__((address_space(1))) void*)g,
      (__attribute__((address_space(3))) void*)l, 16, 0, 0);
}

// ---------------- row sums ----------------
__global__ void rowsum_k(const float* __restrict__ x, float* __restrict__ row_sum) {
  const int row = blockIdx.x;
  const f32x4* xr = (const f32x4*)(x + (size_t)row * IND);
  float s = 0.f;
  for (int i = threadIdx.x; i < IND / 4; i += 256) {
    f32x4 v = xr[i];
    s += (v[0] + v[1]) + (v[2] + v[3]);
  }
#pragma unroll
  for (int o = 32; o > 0; o >>= 1) s += __shfl_down(s, o, 64);
  __shared__ float ws4[4];
  if ((threadIdx.x & 63) == 0) ws4[threadIdx.x >> 6] = s;
  __syncthreads();
  if (threadIdx.x == 0) row_sum[row] = (ws4[0] + ws4[1]) + (ws4[2] + ws4[3]);
}

// ---------------- median + per-row scale ----------------
__global__ void median_scale_k(const float* __restrict__ row_sum,
                               float* __restrict__ sArr, float* __restrict__ invs) {
  __shared__ float v[B_];
  const int tid = threadIdx.x;  // 1024 threads
  v[tid] = row_sum[tid];
  v[tid + 1024] = row_sum[tid + 1024];
  __syncthreads();
  for (int k = 2; k <= B_; k <<= 1) {
    for (int j = k >> 1; j > 0; j >>= 1) {
      for (int i = tid; i < B_; i += 1024) {
        int ixj = i ^ j;
        if (ixj > i) {
          bool up = ((i & k) == 0);
          float a = v[i], b = v[ixj];
          if ((a > b) == up) { v[i] = b; v[ixj] = a; }
        }
      }
      __syncthreads();
    }
  }
  float med = 0.5f * (v[B_ / 2 - 1] + v[B_ / 2]);
  for (int i = tid; i < B_; i += 1024) {
    float rs = row_sum[i];
    sArr[i] = rs / med;
    invs[i] = med / rs;
  }
}

// ---------------- pass2: L = bf16(log1p(x*invs)), partial col sums/sumsq ----------------
__global__ void pass2_k(const float* __restrict__ x, const float* __restrict__ invs,
                        bf16* __restrict__ L, float* __restrict__ part_s,
                        float* __restrict__ part_q) {
  const int c0 = (blockIdx.x * 256 + threadIdx.x) * 4;   // 0..20476
  const int rblk = blockIdx.y;
  const int r0 = rblk * 32;
  const bool valid = (c0 < IND);
  f32x4 sum = {0.f, 0.f, 0.f, 0.f}, sq = {0.f, 0.f, 0.f, 0.f};
  for (int r = r0; r < r0 + 32; ++r) {
    f32x4 lv = {0.f, 0.f, 0.f, 0.f};
    if (valid) {
      f32x4 v = *(const f32x4*)(x + (size_t)r * IND + c0);
      float iv = invs[r];
      lv[0] = log1pf(v[0] * iv); lv[1] = log1pf(v[1] * iv);
      lv[2] = log1pf(v[2] * iv); lv[3] = log1pf(v[3] * iv);
      sum += lv; sq += lv * lv;
    }
    ushort4 o;
    o.x = f2bfu(lv[0]); o.y = f2bfu(lv[1]); o.z = f2bfu(lv[2]); o.w = f2bfu(lv[3]);
    *(ushort4*)((u16*)L + (size_t)r * KP1 + c0) = o;
  }
  if (valid) {
    *(f32x4*)(part_s + (size_t)rblk * KP1 + c0) = sum;
    *(f32x4*)(part_q + (size_t)rblk * KP1 + c0) = sq;
  }
}

// ---------------- finalize BN0 from 64 partials ----------------
__global__ void finalize_bn_k(const float* __restrict__ part_s, const float* __restrict__ part_q,
                              const float* __restrict__ g, const float* __restrict__ b,
                              float* __restrict__ scale, float* __restrict__ shift) {
  int c = blockIdx.x * 256 + threadIdx.x;
  if (c >= IND) return;
  float s = 0.f, q = 0.f;
  for (int z = 0; z < 64; ++z) {
    s += part_s[(size_t)z * KP1 + c];
    q += part_q[(size_t)z * KP1 + c];
  }
  const float invN = 1.f / (float)B_;
  float mean = s * invN;
  float var = q * invN - mean * mean;
  float sc = g[c] * rsqrtf(var + BNEPS);
  scale[c] = sc;
  shift[c] = b[c] - mean * sc;
}

// ---------------- W' = bf16(enc_W * scale0), bias1 = enc_b + shift0 . enc_W^T ----------------
__global__ void prepw_k(const float* __restrict__ encW, const float* __restrict__ enc_b,
                        const float* __restrict__ scale0, const float* __restrict__ shift0,
                        bf16* __restrict__ Wp, float* __restrict__ bias1) {
  const int e = blockIdx.x;  // 512
  float local = 0.f;
  for (int j0 = threadIdx.x * 4; j0 < KP1; j0 += 1024) {
    ushort4 o;
    if (j0 < IND) {
      f32x4 w = *(const f32x4*)(encW + (size_t)e * IND + j0);
      f32x4 sc = *(const f32x4*)(scale0 + j0);
      f32x4 sh = *(const f32x4*)(shift0 + j0);
      local += sh[0] * w[0] + sh[1] * w[1] + sh[2] * w[2] + sh[3] * w[3];
      o.x = f2bfu(w[0] * sc[0]); o.y = f2bfu(w[1] * sc[1]);
      o.z = f2bfu(w[2] * sc[2]); o.w = f2bfu(w[3] * sc[3]);
    } else {
      o.x = 0; o.y = 0; o.z = 0; o.w = 0;
    }
    *(ushort4*)((u16*)Wp + (size_t)e * KP1 + j0) = o;
  }
#pragma unroll
  for (int o = 32; o > 0; o >>= 1) local += __shfl_down(local, o, 64);
  __shared__ float red[4];
  if ((threadIdx.x & 63) == 0) red[threadIdx.x >> 6] = local;
  __syncthreads();
  if (threadIdx.x == 0) bias1[e] = enc_b[e] + ((red[0] + red[1]) + (red[2] + red[3]));
}

// ---------------- 256x256 8-wave 8-PHASE counted-vmcnt GEMM (m201 port) ----------------
// A[M][Kpad] bf16, B[N][Kpad] bf16, C = A.B^T
// LDS: [2 slots][2 halves][128][64] for A and B (128 KiB total).
// Wave layout: wr=wave>>2 (M), wc=wave&3 (N); m-frag row = m*32 + wr*16 + lrow
// (m-interleaved so phase p's m-pair {2p,2p+1} reads one A-half).
// Stage schedule per iter (Ktile e=2t phases1-4 slot0, e+1 phases5-8 slot1):
//  PH1:A1(e+1) PH2:B0(e+2) PH3:B1(e+2) PH4:A0(e+2)+vmcnt(6)
//  PH5:A1(e+2) PH6:B0(e+3) PH7:B1(e+3) PH8:A0(e+3)+vmcnt(6)
// MODE 0: split-K f32x4 partial; 1: sigmoid; 2: exp + s*exp dual; 3: exp
template <int MODE>
__global__ __launch_bounds__(512, 2)
void gemm256(const bf16* __restrict__ A, const bf16* __restrict__ Bm,
             int Kpad, int ksteps,
             float* __restrict__ out0, float* __restrict__ out1,
             const float* __restrict__ bias, const float* __restrict__ sArr,
             int ldo, int Nlimit) {
  extern __shared__ __align__(16) bf16 smem[];  // 128 KiB
  bf16* Asm = smem;           // 32768 elements
  bf16* Bsm = smem + 32768;
  const int tid = threadIdx.x;
  const int lane = tid & 63;
  const int wave = tid >> 6;
  const int wr = wave >> 2;
  const int wc = wave & 3;

  // chunked XCD swizzle (nwg % 8 == 0 for all grids)
  const int nwg = gridDim.x;
  const int q8 = nwg >> 3;
  const int bid = blockIdx.x;
  const int swz = (bid & 7) * q8 + (bid >> 3);
  const int xm = swz & 7;
  const int rest = swz >> 3;
  int yn, z;
  if (MODE == 0) { yn = rest & 1; z = rest >> 1; } else { yn = rest; z = 0; }
  const int m0 = xm * 256;
  const int n0 = yn * 256;
  const int kbeg = z * ksteps * 64;

  // staging: linear LDS dest + pre-swizzled source chunk (both-sides swizzle)
  const int srow = tid >> 3;                    // 0..63
  const int schunk = (tid & 7) ^ (srow & 7);
  const bf16* gA = A + (size_t)(m0 + srow) * Kpad + kbeg + schunk * 8;
  const bf16* gB = Bm + (size_t)(n0 + srow) * Kpad + kbeg + schunk * 8;
  const int dst1 = tid * 8;   // lane0 value = wave*512 elts (wave-uniform base)

  const int lrow = lane & 15;
  const int kq = lane >> 4;   // 0..3
  const int rsw = lrow & 7;

  f32x4 acc[8][4] = {};
  bf16x8 bfv[4][2];

  auto SA = [&](int kt, int half) {
    const bf16* g = gA + (size_t)(half * 128) * Kpad + (size_t)kt * 64;
    bf16* l = Asm + (((kt & 1) * 2 + half) << 13) + dst1;
    gload_lds16(g, l);
    gload_lds16(g + (size_t)64 * Kpad, l + 4096);
  };
  auto SB = [&](int kt, int half) {
    const bf16* g = gB + (size_t)(half * 128) * Kpad + (size_t)kt * 64;
    bf16* l = Bsm + (((kt & 1) * 2 + half) << 13) + dst1;
    gload_lds16(g, l);
    gload_lds16(g + (size_t)64 * Kpad, l + 4096);
  };
  auto DSA = [&](int slot, int p, bf16x8 af[2][2]) {
#pragma unroll
    for (int i = 0; i < 2; ++i) {
      const int m = 2 * p + i;
      const int base = ((slot * 2 + (m >> 2)) * 128 + (m & 3) * 32 + wr * 16 + lrow) * 64;
#pragma unroll
      for (int kk = 0; kk < 2; ++kk)
        af[i][kk] = *(const bf16x8*)(&Asm[base + (((kk * 4 + kq) ^ rsw) << 3)]);
    }
  };
  auto DSB = [&](int slot) {
#pragma unroll
    for (int n = 0; n < 4; ++n) {
      const int base = ((slot * 2 + (wc >> 1)) * 128 + (wc & 1) * 64 + n * 16 + lrow) * 64;
#pragma unroll
      for (int kk = 0; kk < 2; ++kk)
        bfv[n][kk] = *(const bf16x8*)(&Bsm[base + (((kk * 4 + kq) ^ rsw) << 3)]);
    }
  };
  auto MF = [&](int p, bf16x8 af[2][2]) {
    __builtin_amdgcn_s_setprio(1);
#pragma unroll
    for (int i = 0; i < 2; ++i)
#pragma unroll
      for (int n = 0; n < 4; ++n)
#pragma unroll
        for (int kk = 0; kk < 2; ++kk)
          acc[2 * p + i][n] = __builtin_amdgcn_mfma_f32_16x16x32_bf16(
              bfv[n][kk], af[i][kk], acc[2 * p + i][n], 0, 0, 0);
    __builtin_amdgcn_s_setprio(0);
  };

  // prologue: Ktile0 complete (4 half-tiles) + {B0,B1,A0}(Ktile1)
  SA(0, 0); SA(0, 1); SB(0, 0); SB(0, 1);
  SB(1, 0); SB(1, 1); SA(1, 0);
  asm volatile("s_waitcnt vmcnt(6)" ::: "memory");  // Ktile0 landed
  __builtin_amdgcn_s_barrier();

  const int iters = ksteps >> 1;
  for (int t = 0; t < iters; ++t) {
    const int e = 2 * t;
    const bool last = (t == iters - 1);
    bf16x8 af[2][2];
    // ---- PH1: Ktile e, m-pair 0 (+ B regs) ----
    DSB(0); DSA(0, 0, af);
    SA(e + 1, 1);                       // completes Ktile e+1
    __builtin_amdgcn_s_barrier();
    MF(0, af);
    __builtin_amdgcn_s_barrier();
    // ---- PH2 ----
    DSA(0, 1, af);
    if (!last) SB(e + 2, 0);            // B-slot0 free after PH1
    __builtin_amdgcn_s_barrier();
    MF(1, af);
    __builtin_amdgcn_s_barrier();
    // ---- PH3 ----
    DSA(0, 2, af);
    if (!last) SB(e + 2, 1);
    __builtin_amdgcn_s_barrier();
    MF(2, af);
    __builtin_amdgcn_s_barrier();
    // ---- PH4 ----
    DSA(0, 3, af);
    if (!last) SA(e + 2, 0);            // A0-slot0 free after PH2
    if (last) { asm volatile("s_waitcnt vmcnt(0)" ::: "memory"); }
    else      { asm volatile("s_waitcnt vmcnt(6)" ::: "memory"); }  // Ktile e+1 landed
    __builtin_amdgcn_s_barrier();
    MF(3, af);
    __builtin_amdgcn_s_barrier();
    // ---- PH5: Ktile e+1, slot1 ----
    DSB(1); DSA(1, 0, af);
    if (!last) SA(e + 2, 1);            // A1-slot0 free after PH4
    __builtin_amdgcn_s_barrier();
    MF(0, af);
    __builtin_amdgcn_s_barrier();
    // ---- PH6 ----
    DSA(1, 1, af);
    if (!last) SB(e + 3, 0);            // B-slot1 free after PH5
    __builtin_amdgcn_s_barrier();
    MF(1, af);
    __builtin_amdgcn_s_barrier();
    // ---- PH7 ----
    DSA(1, 2, af);
    if (!last) SB(e + 3, 1);
    __builtin_amdgcn_s_barrier();
    MF(2, af);
    __builtin_amdgcn_s_barrier();
    // ---- PH8 ----
    DSA(1, 3, af);
    if (!last) SA(e + 3, 0);            // A0-slot1 free after PH6
    if (last) { asm volatile("s_waitcnt vmcnt(0)" ::: "memory"); }
    else      { asm volatile("s_waitcnt vmcnt(6)" ::: "memory"); }  // Ktile e+2 landed
    __builtin_amdgcn_s_barrier();
    MF(3, af);
    __builtin_amdgcn_s_barrier();
  }

  float* o0 = out0;
  if (MODE == 0) o0 += (size_t)z * ((size_t)B_ * ldo);
  const int gcolb = n0 + wc * 64 + kq * 4;
#pragma unroll
  for (int m = 0; m < 8; ++m) {
    const int grow = m0 + m * 32 + wr * 16 + lrow;   // m-interleaved rows
    float srow_s = 0.f;
    if (MODE == 2) srow_s = sArr[grow];
#pragma unroll
    for (int n = 0; n < 4; ++n) {
      const int gcol = gcolb + n * 16;
      f32x4 v = acc[m][n];
      if (MODE == 0) {
        *(f32x4*)(&o0[(size_t)grow * ldo + gcol]) = v;
      } else if (gcol < Nlimit) {
        f32x4 bb = *(const f32x4*)(&bias[gcol]);
        f32x4 t = v + bb;
        f32x4 r;
        if (MODE == 1) {
#pragma unroll
          for (int j = 0; j < 4; ++j) r[j] = 1.f / (1.f + __expf(-t[j]));
          *(f32x4*)(&o0[(size_t)grow * ldo + gcol]) = r;
        } else if (MODE == 2) {
#pragma unroll
          for (int j = 0; j < 4; ++j) r[j] = __expf(t[j]);
          *(f32x4*)(&o0[(size_t)grow * ldo + gcol]) = r;
          f32x4 rl;
#pragma unroll
          for (int j = 0; j < 4; ++j) rl[j] = srow_s * r[j];
          *(f32x4*)(&out1[(size_t)grow * ldo + gcol]) = rl;
        } else {
#pragma unroll
          for (int j = 0; j < 4; ++j) r[j] = __expf(t[j]);
          *(f32x4*)(&o0[(size_t)grow * ldo + gcol]) = r;
        }
      }
    }
  }
}

// ---------------- 128x128 4-wave GEMM for small layers (bias+relu epilogues) ----------------
// MODE 4: f32 out; MODE 5: bf16 out
template <int MODE>
__global__ __launch_bounds__(256, 2)
void gemm128(const bf16* __restrict__ A, const bf16* __restrict__ Bm,
             int Kpad, int ksteps,
             float* __restrict__ outF, bf16* __restrict__ outB,
             const float* __restrict__ bias, int ldo) {
  __shared__ __align__(16) bf16 As[2][128 * 64];
  __shared__ __align__(16) bf16 Bs[2][128 * 64];
  const int tid = threadIdx.x;
  const int wave = tid >> 6;
  const int lane = tid & 63;
  const int wr = wave >> 1, wc = wave & 1;
  const int m0 = blockIdx.x * 128;
  const int n0 = blockIdx.y * 128;

  const int srow = wave * 32 + (lane >> 3);
  const int scol = ((lane & 7) ^ (lane >> 3)) * 8;
  const bf16* gA = A + (size_t)(m0 + srow) * Kpad + scol;
  const bf16* gB = Bm + (size_t)(n0 + srow) * Kpad + scol;
  const int lbase = wave * 2048;

  f32x4 acc[4][4] = {};
  const int lrow = lane & 15;
  const int swz = lrow & 7;
  const int kq = lane >> 4;

  auto STAGE = [&](int ks, int buf) {
    const bf16* ga = gA + (size_t)ks * 64;
    const bf16* gb = gB + (size_t)ks * 64;
#pragma unroll
    for (int i = 0; i < 4; ++i) {
      gload_lds16(ga + (size_t)(i * 8) * Kpad, &As[buf][lbase + i * 512]);
      gload_lds16(gb + (size_t)(i * 8) * Kpad, &Bs[buf][lbase + i * 512]);
    }
  };

  STAGE(0, 0);
  asm volatile("s_waitcnt vmcnt(0)" ::: "memory");
  __builtin_amdgcn_s_barrier();

  int cur = 0;
  for (int ks = 0; ks < ksteps; ++ks) {
    if (ks + 1 < ksteps) STAGE(ks + 1, cur ^ 1);
#pragma unroll
    for (int kk = 0; kk < 2; ++kk) {
      const int kc = kk * 4 + kq;
      bf16x8 af[4], bfv[4];
#pragma unroll
      for (int m = 0; m < 4; ++m) {
        const int row = wr * 64 + m * 16 + lrow;
        af[m] = *(const bf16x8*)(&As[cur][row * 64 + (((kc ^ swz) & 7) << 3)]);
      }
#pragma unroll
      for (int n = 0; n < 4; ++n) {
        const int row = wc * 64 + n * 16 + lrow;
        bfv[n] = *(const bf16x8*)(&Bs[cur][row * 64 + (((kc ^ swz) & 7) << 3)]);
      }
#pragma unroll
      for (int m = 0; m < 4; ++m)
#pragma unroll
        for (int n = 0; n < 4; ++n)
          acc[m][n] = __builtin_amdgcn_mfma_f32_16x16x32_bf16(bfv[n], af[m], acc[m][n], 0, 0, 0);
    }
    if (ks + 1 < ksteps) {
      asm volatile("s_waitcnt vmcnt(0)" ::: "memory");
      __builtin_amdgcn_s_barrier();
      cur ^= 1;
    }
  }

  const int growb = m0 + wr * 64 + lrow;
  const int gcolb = n0 + wc * 64 + kq * 4;
#pragma unroll
  for (int m = 0; m < 4; ++m) {
    const int grow = growb + m * 16;
#pragma unroll
    for (int n = 0; n < 4; ++n) {
      const int gcol = gcolb + n * 16;
      f32x4 bb = *(const f32x4*)(&bias[gcol]);
      f32x4 t = acc[m][n] + bb;
      if (MODE == 4) {
        f32x4 r;
#pragma unroll
        for (int j = 0; j < 4; ++j) r[j] = fmaxf(t[j], 0.f);
        *(f32x4*)(&outF[(size_t)grow * ldo + gcol]) = r;
      } else {
        ushort4 o;
        o.x = f2bfu(fmaxf(t[0], 0.f)); o.y = f2bfu(fmaxf(t[1], 0.f));
        o.z = f2bfu(fmaxf(t[2], 0.f)); o.w = f2bfu(fmaxf(t[3], 0.f));
        *(ushort4*)((u16*)outB + (size_t)grow * ldo + gcol) = o;
      }
    }
  }
}

// ---------------- split-K reduce + bias + relu -> C1 ----------------
__global__ void reduce1_k(const float* __restrict__ Cp, const float* __restrict__ bias1,
                          float* __restrict__ C1) {
  const size_t i4 = ((size_t)blockIdx.x * 256 + threadIdx.x) * 4;
  f32x4 t = {0.f, 0.f, 0.f, 0.f};
#pragma unroll
  for (int z = 0; z < SPLITK; ++z) t += *(const f32x4*)(Cp + (size_t)z * (B_ * ENCN) + i4);
  f32x4 bb = *(const f32x4*)(bias1 + (i4 & (ENCN - 1)));
  t += bb;
  f32x4 r;
#pragma unroll
  for (int j = 0; j < 4; ++j) r[j] = fmaxf(t[j], 0.f);
  *(f32x4*)(C1 + i4) = r;
}

// ---------------- column stats, 2-stage ----------------
__global__ void colpart_k(const float* __restrict__ X, int C,
                          float* __restrict__ ps, float* __restrict__ pq) {
  const int cl = threadIdx.x & 63;
  const int rg = threadIdx.x >> 6;
  const int c = blockIdx.x * 64 + cl;
  const int r0 = blockIdx.y * 64 + rg * 16;
  float sum = 0.f, sq = 0.f;
  for (int rr = 0; rr < 16; ++rr) {
    float v = X[(size_t)(r0 + rr) * C + c];
    sum += v; sq += v * v;
  }
  __shared__ float ls[4][64], lq[4][64];
  ls[rg][cl] = sum; lq[rg][cl] = sq;
  __syncthreads();
  if (rg == 0) {
    sum = (ls[0][cl] + ls[1][cl]) + (ls[2][cl] + ls[3][cl]);
    sq = (lq[0][cl] + lq[1][cl]) + (lq[2][cl] + lq[3][cl]);
    ps[(size_t)blockIdx.y * C + c] = sum;
    pq[(size_t)blockIdx.y * C + c] = sq;
  }
}

__global__ void colfin_k(const float* __restrict__ ps, const float* __restrict__ pq,
                         const float* __restrict__ g, const float* __restrict__ b,
                         float* __restrict__ scale, float* __restrict__ shift, int C) {
  int c = blockIdx.x * 256 + threadIdx.x;
  if (c >= C) return;
  float sum = 0.f, sq = 0.f;
  for (int z = 0; z < 32; ++z) {
    sum += ps[(size_t)z * C + c];
    sq += pq[(size_t)z * C + c];
  }
  const float invN = 1.f / (float)B_;
  float mean = sum * invN;
  float var = sq * invN - mean * mean;
  float sc = g[c] * rsqrtf(var + BNEPS);
  scale[c] = sc;
  shift[c] = b[c] - mean * sc;
}

// ---------------- affine (BN) + bf16 cvt ----------------
__global__ void affine_k(const float* __restrict__ X, const float* __restrict__ sc,
                         const float* __restrict__ sh, bf16* __restrict__ out, int Cm1) {
  const size_t i4 = ((size_t)blockIdx.x * 256 + threadIdx.x) * 4;
  const int c0 = (int)(i4 & (size_t)Cm1);
  f32x4 v = *(const f32x4*)(X + i4);
  f32x4 s = *(const f32x4*)(sc + c0);
  f32x4 h = *(const f32x4*)(sh + c0);
  f32x4 t = v * s + h;
  ushort4 o;
  o.x = f2bfu(t[0]); o.y = f2bfu(t[1]); o.z = f2bfu(t[2]); o.w = f2bfu(t[3]);
  *(ushort4*)((u16*)out + i4) = o;
}

// ---------------- plain f32 -> bf16 cvt ----------------
__global__ void cvtw_k(const float* __restrict__ src, bf16* __restrict__ dst) {
  const size_t i4 = ((size_t)blockIdx.x * 256 + threadIdx.x) * 4;
  f32x4 v = *(const f32x4*)(src + i4);
  ushort4 o;
  o.x = f2bfu(v[0]); o.y = f2bfu(v[1]); o.z = f2bfu(v[2]); o.w = f2bfu(v[3]);
  *(ushort4*)((u16*)dst + i4) = o;
}

// ---------------- output weight cvt with row pad to NP ----------------
__global__ void cvt_o_k(const float* __restrict__ Wsrc, bf16* __restrict__ Wb) {
  const size_t idx = ((size_t)blockIdx.x * 256 + threadIdx.x) * 4;  // < NP*512
  const int e = (int)(idx >> 9);
  ushort4 o;
  if (e < IND) {
    f32x4 v = *(const f32x4*)(Wsrc + idx);
    o.x = f2bfu(v[0]); o.y = f2bfu(v[1]); o.z = f2bfu(v[2]); o.w = f2bfu(v[3]);
  } else {
    o.x = 0; o.y = 0; o.z = 0; o.w = 0;
  }
  *(ushort4*)((u16*)Wb + idx) = o;
}

extern "C" void kernel_launch(void* const* d_in, const int* in_sizes, int n_in,
                              void* d_out, int out_size, void* d_ws, size_t ws_size,
                              hipStream_t stream) {
  const float* x     = (const float*)d_in[0];
  const float* bn0_g = (const float*)d_in[1];
  const float* bn0_b = (const float*)d_in[2];
  const float* enc_W = (const float*)d_in[3];
  const float* enc_b = (const float*)d_in[4];
  const float* bn1_g = (const float*)d_in[5];
  const float* bn1_b = (const float*)d_in[6];
  const float* bot_W = (const float*)d_in[7];
  const float* bot_b = (const float*)d_in[8];
  const float* bn2_g = (const float*)d_in[9];
  const float* bn2_b = (const float*)d_in[10];
  const float* dec_W = (const float*)d_in[11];
  const float* dec_b = (const float*)d_in[12];
  const float* o1_W  = (const float*)d_in[13];
  const float* o1_b  = (const float*)d_in[14];
  const float* o2_W  = (const float*)d_in[15];
  const float* o2_b  = (const float*)d_in[16];
  const float* o3_W  = (const float*)d_in[17];
  const float* o3_b  = (const float*)d_in[18];

  char* wsb = (char*)d_ws;
  size_t off = 0;
  auto alloc = [&](size_t bytes) -> void* {
    void* p = wsb + off;
    off = (off + bytes + 255) & ~(size_t)255;
    return p;
  };
  float* row_sum = (float*)alloc(B_ * 4);
  float* sArr    = (float*)alloc(B_ * 4);
  float* invs    = (float*)alloc(B_ * 4);
  float* scale0  = (float*)alloc(IND * 4);
  float* shift0  = (float*)alloc(IND * 4);
  float* bias1   = (float*)alloc(ENCN * 4);
  float* scale1  = (float*)alloc(ENCN * 4);
  float* shift1  = (float*)alloc(ENCN * 4);
  float* scale2  = (float*)alloc(BOTN * 4);
  float* shift2  = (float*)alloc(BOTN * 4);
  float* ps1     = (float*)alloc(32 * ENCN * 4);
  float* pq1     = (float*)alloc(32 * ENCN * 4);
  float* ps2     = (float*)alloc(32 * BOTN * 4);
  float* pq2     = (float*)alloc(32 * BOTN * 4);
  float* C1      = (float*)alloc((size_t)B_ * ENCN * 4);
  float* C2f     = (float*)alloc((size_t)B_ * BOTN * 4);
  float* Cp      = (float*)alloc((size_t)SPLITK * B_ * ENCN * 4);
  bf16*  L       = (bf16*)alloc((size_t)B_ * KP1 * 2);
  bf16*  Wp      = (bf16*)alloc((size_t)ENCN * KP1 * 2);
  bf16*  A1b     = (bf16*)alloc((size_t)B_ * ENCN * 2);
  bf16*  A2b     = (bf16*)alloc((size_t)B_ * BOTN * 2);
  bf16*  botWb   = (bf16*)alloc((size_t)BOTN * ENCN * 2);
  bf16*  decWb   = (bf16*)alloc((size_t)DECN * BOTN * 2);
  bf16*  h3      = (bf16*)alloc((size_t)B_ * DECN * 2);
  bf16*  wbf0    = (bf16*)alloc((size_t)NP * 512 * 2);
  bf16*  wbf1    = (bf16*)alloc((size_t)NP * 512 * 2);
  bf16*  wbf2    = (bf16*)alloc((size_t)NP * 512 * 2);
  // BN0 partials alias Cp (dead before GEMM1 writes Cp)
  float* part_s  = Cp;
  float* part_q  = Cp + (size_t)64 * KP1;

  hipFuncSetAttribute(reinterpret_cast<const void*>(gemm256<0>),
                      hipFuncAttributeMaxDynamicSharedMemorySize, 131072);
  hipFuncSetAttribute(reinterpret_cast<const void*>(gemm256<1>),
                      hipFuncAttributeMaxDynamicSharedMemorySize, 131072);
  hipFuncSetAttribute(reinterpret_cast<const void*>(gemm256<2>),
                      hipFuncAttributeMaxDynamicSharedMemorySize, 131072);
  hipFuncSetAttribute(reinterpret_cast<const void*>(gemm256<3>),
                      hipFuncAttributeMaxDynamicSharedMemorySize, 131072);

  // 1. row sums + median scales
  rowsum_k<<<B_, 256, 0, stream>>>(x, row_sum);
  median_scale_k<<<1, 1024, 0, stream>>>(row_sum, sArr, invs);

  // 2. L = bf16(log1p(x/s)), BN0 stats
  pass2_k<<<dim3(KP1 / 1024, 64), 256, 0, stream>>>(x, invs, L, part_s, part_q);
  finalize_bn_k<<<(IND + 255) / 256, 256, 0, stream>>>(part_s, part_q, bn0_g, bn0_b,
                                                       scale0, shift0);

  // 3. fold BN0 into encoder weights
  prepw_k<<<ENCN, 256, 0, stream>>>(enc_W, enc_b, scale0, shift0, Wp, bias1);

  // 4. GEMM1 (256^2 8-phase, split-K=16) + reduce(+bias+relu) -> C1
  gemm256<0><<<8 * 2 * SPLITK, 512, 131072, stream>>>(
      L, Wp, KP1, KSTEP1, Cp, nullptr, nullptr, nullptr, ENCN, ENCN);
  reduce1_k<<<(B_ * ENCN) / 1024, 256, 0, stream>>>(Cp, bias1, C1);

  // 5. BN1 -> GEMM2 (MFMA) -> C2; BN2 -> GEMM3 (MFMA) -> h3 bf16
  colpart_k<<<dim3(ENCN / 64, 32), 256, 0, stream>>>(C1, ENCN, ps1, pq1);
  colfin_k<<<2, 256, 0, stream>>>(ps1, pq1, bn1_g, bn1_b, scale1, shift1, ENCN);
  affine_k<<<(B_ * ENCN) / 1024, 256, 0, stream>>>(C1, scale1, shift1, A1b, ENCN - 1);
  cvtw_k<<<(BOTN * ENCN) / 1024, 256, 0, stream>>>(bot_W, botWb);
  gemm128<4><<<dim3(16, 1), 256, 0, stream>>>(A1b, botWb, ENCN, ENCN / 64,
                                              C2f, nullptr, bot_b, BOTN);
  colpart_k<<<dim3(BOTN / 64, 32), 256, 0, stream>>>(C2f, BOTN, ps2, pq2);
  colfin_k<<<1, 256, 0, stream>>>(ps2, pq2, bn2_g, bn2_b, scale2, shift2, BOTN);
  affine_k<<<(B_ * BOTN) / 1024, 256, 0, stream>>>(C2f, scale2, shift2, A2b, BOTN - 1);
  cvtw_k<<<(DECN * BOTN) / 1024, 256, 0, stream>>>(dec_W, decWb);
  gemm128<5><<<dim3(16, 4), 256, 0, stream>>>(A2b, decWb, BOTN, BOTN / 64,
                                              nullptr, h3, dec_b, DECN);

  // 6. convert output weights to bf16 (padded rows = 0)
  const int cvtg = (NP * 512) / 1024;
  cvt_o_k<<<cvtg, 256, 0, stream>>>(o1_W, wbf0);
  cvt_o_k<<<cvtg, 256, 0, stream>>>(o2_W, wbf1);
  cvt_o_k<<<cvtg, 256, 0, stream>>>(o3_W, wbf2);

  // 7. output GEMMs (256^2 8-phase) with fused epilogues
  float* out = (float*)d_out;
  const size_t OFF = (size_t)B_ * IND;
  const int onwg = 8 * (NP / 256);  // 632, divisible by 8
  gemm256<1><<<onwg, 512, 131072, stream>>>(
      h3, wbf1, 512, 8, out, nullptr, o2_b, nullptr, IND, IND);
  gemm256<2><<<onwg, 512, 131072, stream>>>(
      h3, wbf0, 512, 8, out + OFF, out + 3 * OFF, o1_b, sArr, IND, IND);
  gemm256<3><<<onwg, 512, 131072, stream>>>(
      h3, wbf2, 512, 8, out + 2 * OFF, nullptr, o3_b, nullptr, IND, IND);
}